// Round 1
// baseline (239.540 us; speedup 1.0000x reference)
//
#include <hip/hip_runtime.h>

#define B  16
#define N  256
#define F  128
#define NB 32
#define INF_F 1000000000.0f

// ---------------------------------------------------------------------------
// Kernel 1: D0 = where(adj>0, adj, INF); diag = 0
// ---------------------------------------------------------------------------
__global__ __launch_bounds__(256) void k_init(const float* __restrict__ adj,
                                              float* __restrict__ D) {
    int idx = blockIdx.x * blockDim.x + threadIdx.x;  // over B*N*N
    if (idx >= B * N * N) return;
    int j = idx & (N - 1);
    int i = (idx >> 8) & (N - 1);
    float a = adj[idx];
    float d = (a > 0.0f) ? a : INF_F;
    if (i == j) d = 0.0f;
    D[idx] = d;
}

// ---------------------------------------------------------------------------
// Kernel 2: one min-plus squaring step: Dout[i,j] = min_k Din[i,k] + Din[k,j]
// 64x64 tile per block, 256 threads, 4x4 accumulators, k-tiles of 32.
// Adds are plain fp32 adds (no mul -> no contraction), min is fminf:
// bitwise identical to the reference reduction.
// ---------------------------------------------------------------------------
__global__ __launch_bounds__(256) void k_minplus(const float* __restrict__ Din,
                                                 float* __restrict__ Dout) {
    int blk = blockIdx.x;           // B * 4 * 4 = 256 blocks
    int b  = blk >> 4;
    int bi = (blk >> 2) & 3;
    int bj = blk & 3;
    const float* Db = Din + b * N * N;

    __shared__ float As[64][32];    // [i][k]
    __shared__ float Bs[32][64];    // [k][j]

    int tid = threadIdx.x;
    int tx = tid & 15;
    int ty = tid >> 4;

    float acc[4][4];
#pragma unroll
    for (int r = 0; r < 4; ++r)
#pragma unroll
        for (int c = 0; c < 4; ++c) acc[r][c] = 3.0e38f;

    float ra[8], rb[8];
    // prologue: load k-tile 0 to registers (coalesced; LDS-write bank-clean:
    // lin = u*256 + tid -> write bank = tid % 32)
#pragma unroll
    for (int u = 0; u < 8; ++u) {
        int lin = u * 256 + tid;
        ra[u] = Db[(bi * 64 + (lin >> 5)) * N + (lin & 31)];
        rb[u] = Db[(lin >> 6) * N + bj * 64 + (lin & 63)];
    }

    for (int kt = 0; kt < 8; ++kt) {
#pragma unroll
        for (int u = 0; u < 8; ++u) {
            int lin = u * 256 + tid;
            As[lin >> 5][lin & 31] = ra[u];
            Bs[lin >> 6][lin & 63] = rb[u];
        }
        __syncthreads();
        if (kt < 7) {  // prefetch next k-tile while computing this one
            int kb = (kt + 1) * 32;
#pragma unroll
            for (int u = 0; u < 8; ++u) {
                int lin = u * 256 + tid;
                ra[u] = Db[(bi * 64 + (lin >> 5)) * N + kb + (lin & 31)];
                rb[u] = Db[(kb + (lin >> 6)) * N + bj * 64 + (lin & 63)];
            }
        }
#pragma unroll
        for (int k = 0; k < 32; ++k) {
            float av[4];
            av[0] = As[ty * 4 + 0][k];
            av[1] = As[ty * 4 + 1][k];
            av[2] = As[ty * 4 + 2][k];
            av[3] = As[ty * 4 + 3][k];
            float4 bq = *(const float4*)&Bs[k][tx * 4];
            float bv[4] = {bq.x, bq.y, bq.z, bq.w};
#pragma unroll
            for (int r = 0; r < 4; ++r)
#pragma unroll
                for (int c = 0; c < 4; ++c)
                    acc[r][c] = fminf(acc[r][c], av[r] + bv[c]);
        }
        __syncthreads();
    }

    float* Ob = Dout + b * N * N;
#pragma unroll
    for (int r = 0; r < 4; ++r) {
        float4 v = make_float4(acc[r][0], acc[r][1], acc[r][2], acc[r][3]);
        *(float4*)&Ob[(bi * 64 + ty * 4 + r) * N + bj * 64 + tx * 4] = v;
    }
}

// ---------------------------------------------------------------------------
// Kernel 3: per row (b,i): select 32 smallest (value, index) pairs, emit
// their indices in ascending index order. Reproduces
// sort(stable_argsort(D_row)[:32]) exactly.
// ---------------------------------------------------------------------------
__global__ __launch_bounds__(256) void k_select(const float* __restrict__ D,
                                                int* __restrict__ nbr) {
    int row = blockIdx.x;           // b*N + i, 0..4095
    int j = threadIdx.x;            // 0..255

    __shared__ unsigned long long keys[256];
    __shared__ int wsum[4];

    float d = D[row * N + j];
    // distances are all >= 0 -> float bit pattern orders numerically
    unsigned long long key =
        ((unsigned long long)__float_as_uint(d) << 32) | (unsigned int)j;
    keys[j] = key;
    __syncthreads();

    int cnt = 0;
#pragma unroll 16
    for (int t = 0; t < 256; ++t) cnt += (keys[t] < key) ? 1 : 0;

    bool flag = (cnt < NB);         // exactly NB threads have rank < NB
    unsigned long long m = __ballot(flag);
    int lane = j & 63;
    int wid = j >> 6;
    if (lane == 0) wsum[wid] = __popcll(m);
    __syncthreads();
    int base = 0;
    for (int w = 0; w < wid; ++w) base += wsum[w];
    int pos = base + __popcll(m & ((1ull << lane) - 1ull));
    if (flag) nbr[row * NB + pos] = j;
}

// ---------------------------------------------------------------------------
// Kernel 4: sub_f[b,i,r,:] = features[b, nbr[b,i,r], :]   (float4 per thread)
// ---------------------------------------------------------------------------
__global__ __launch_bounds__(256) void k_gather_f(const float* __restrict__ feat,
                                                  const int* __restrict__ nbr,
                                                  float* __restrict__ outF) {
    int gid = blockIdx.x * blockDim.x + threadIdx.x;   // B*N*NB*(F/4) = 4M
    if (gid >= B * N * NB * (F / 4)) return;
    int c4  = gid & 31;             // F/4 = 32
    int r   = (gid >> 5) & 31;      // NB
    int row = gid >> 10;            // b*N + i
    int b   = row >> 8;
    int nj = nbr[row * NB + r];
    float4 v = *(const float4*)&feat[((b << 8) + nj) * F + (c4 << 2)];
    ((float4*)outF)[gid] = v;
}

// ---------------------------------------------------------------------------
// Kernel 5: fused adj + edge gather.
// sub_a[b,i,r,c]   = adj[b, nr, nc]
// sub_e[b,i,r,c,:] = ef [b, nr, nc, :]
// ---------------------------------------------------------------------------
__global__ __launch_bounds__(256) void k_gather_ae(const float* __restrict__ adj,
                                                   const float* __restrict__ ef,
                                                   const int* __restrict__ nbr,
                                                   float* __restrict__ outA,
                                                   float* __restrict__ outE) {
    int gid = blockIdx.x * blockDim.x + threadIdx.x;   // B*N*NB*NB = 4M
    if (gid >= B * N * NB * NB) return;
    int c   = gid & 31;
    int r   = (gid >> 5) & 31;
    int row = gid >> 10;            // b*N + i
    int b   = row >> 8;
    int nr = nbr[row * NB + r];     // broadcast within 32-thread group
    int nc = nbr[row * NB + c];     // coalesced within group
    int base = (b << 16) + (nr << 8) + nc;   // b*N*N + nr*N + nc
    outA[gid] = adj[base];
    const float* e = ef + (long)base * 3;
    float e0 = e[0], e1 = e[1], e2 = e[2];
    long og = (long)gid * 3;
    outE[og + 0] = e0;
    outE[og + 1] = e1;
    outE[og + 2] = e2;
}

// ---------------------------------------------------------------------------
extern "C" void kernel_launch(void* const* d_in, const int* in_sizes, int n_in,
                              void* d_out, int out_size, void* d_ws, size_t ws_size,
                              hipStream_t stream) {
    const float* feat = (const float*)d_in[0];   // (B,N,F)
    const float* adj  = (const float*)d_in[1];   // (B,N,N)
    const float* ef   = (const float*)d_in[2];   // (B,N,N,3)
    // d_in[3] = neigh_size (==32, compiled in as NB)

    float* out  = (float*)d_out;
    float* outF = out;                                   // B*N*NB*F
    float* outA = out + (size_t)B * N * NB * F;          // B*N*NB*NB
    float* outE = outA + (size_t)B * N * NB * NB;        // B*N*NB*NB*3

    float* D0 = (float*)d_ws;
    float* D1 = D0 + (size_t)B * N * N;
    int*  nbr = (int*)(D1 + (size_t)B * N * N);

    k_init<<<(B * N * N) / 256, 256, 0, stream>>>(adj, D0);

    float* src = D0;
    float* dst = D1;
    for (int s = 0; s < 8; ++s) {   // ceil(log2(255)) = 8 squarings, like ref
        k_minplus<<<B * 16, 256, 0, stream>>>(src, dst);
        float* t = src; src = dst; dst = t;
    }
    // 8 swaps -> result back in D0 (== src)

    k_select<<<B * N, 256, 0, stream>>>(src, nbr);

    k_gather_f<<<(B * N * NB * (F / 4)) / 256, 256, 0, stream>>>(feat, nbr, outF);
    k_gather_ae<<<(B * N * NB * NB) / 256, 256, 0, stream>>>(adj, ef, nbr, outA, outE);
}

// Round 2
// 231.304 us; speedup vs baseline: 1.0356x; 1.0356x over previous
//
#include <hip/hip_runtime.h>

#define B  16
#define N  256
#define F  128
#define NB 32
#define INF_F 1000000000.0f

// ---------------------------------------------------------------------------
// min-plus squaring step: Dout[i,j] = min_k Din[i,k] + Din[k,j]
// 64x64 tile per block, 256 threads, 4x4 acc/thread, k-tiles of 32,
// k unrolled by 4 so both LDS operands are float4 (b128) reads.
// As padded [64][36]: read bank = (4*row+4*kq)%32 -> 2-way (free).
// FIRST fuses the where(adj>0,adj,INF)+diag(0) transform into staging.
// All fp ops identical operand pairs as reference -> bitwise exact.
// ---------------------------------------------------------------------------
template<bool FIRST>
__global__ __launch_bounds__(256) void k_minplus(const float* __restrict__ Din,
                                                 float* __restrict__ Dout) {
    int blk = blockIdx.x;           // B * 4 * 4 = 256 blocks
    int b  = blk >> 4;
    int bi = (blk >> 2) & 3;
    int bj = blk & 3;
    const float* Db = Din + b * N * N;

    __shared__ float As[64][36];    // [i][k], padded for bank-clean b128 reads
    __shared__ float Bs[32][64];    // [k][j]

    int tid = threadIdx.x;
    int tx = tid & 15;
    int ty = tid >> 4;

    float acc[4][4];
#pragma unroll
    for (int r = 0; r < 4; ++r)
#pragma unroll
        for (int c = 0; c < 4; ++c) acc[r][c] = 3.0e38f;

    float ra[8], rb[8];

    // global loads (coalesced); FIRST applies the init transform inline
#define LOAD_A(kb, u) {                                                        \
        int lin = (u) * 256 + tid;                                             \
        int gi = bi * 64 + (lin >> 5);                                         \
        int gk = (kb) + (lin & 31);                                            \
        float v = Db[gi * N + gk];                                             \
        if (FIRST) { v = (v > 0.0f) ? v : INF_F; if (gi == gk) v = 0.0f; }     \
        ra[u] = v; }
#define LOAD_B(kb, u) {                                                        \
        int lin = (u) * 256 + tid;                                             \
        int gk = (kb) + (lin >> 6);                                            \
        int gj = bj * 64 + (lin & 63);                                         \
        float v = Db[gk * N + gj];                                             \
        if (FIRST) { v = (v > 0.0f) ? v : INF_F; if (gk == gj) v = 0.0f; }     \
        rb[u] = v; }

#pragma unroll
    for (int u = 0; u < 8; ++u) { LOAD_A(0, u) LOAD_B(0, u) }

    for (int kt = 0; kt < 8; ++kt) {
#pragma unroll
        for (int u = 0; u < 8; ++u) {
            int lin = u * 256 + tid;
            As[lin >> 5][lin & 31] = ra[u];   // bank (4i+k)%32: conflict-free
            Bs[lin >> 6][lin & 63] = rb[u];   // 2-way: free
        }
        __syncthreads();
        if (kt < 7) {  // prefetch next k-tile into registers during compute
            int kb = (kt + 1) * 32;
#pragma unroll
            for (int u = 0; u < 8; ++u) { LOAD_A(kb, u) LOAD_B(kb, u) }
        }

#define UPD(r, c, av, bv) acc[r][c] = fminf(acc[r][c], (av) + (bv))
#define QSTEP(comp, Bq)                                                        \
        UPD(0,0,A0.comp,Bq.x); UPD(0,1,A0.comp,Bq.y);                          \
        UPD(0,2,A0.comp,Bq.z); UPD(0,3,A0.comp,Bq.w);                          \
        UPD(1,0,A1.comp,Bq.x); UPD(1,1,A1.comp,Bq.y);                          \
        UPD(1,2,A1.comp,Bq.z); UPD(1,3,A1.comp,Bq.w);                          \
        UPD(2,0,A2.comp,Bq.x); UPD(2,1,A2.comp,Bq.y);                          \
        UPD(2,2,A2.comp,Bq.z); UPD(2,3,A2.comp,Bq.w);                          \
        UPD(3,0,A3.comp,Bq.x); UPD(3,1,A3.comp,Bq.y);                          \
        UPD(3,2,A3.comp,Bq.z); UPD(3,3,A3.comp,Bq.w)

#pragma unroll
        for (int kq = 0; kq < 8; ++kq) {
            float4 A0 = *(const float4*)&As[ty * 4 + 0][kq * 4];
            float4 A1 = *(const float4*)&As[ty * 4 + 1][kq * 4];
            float4 A2 = *(const float4*)&As[ty * 4 + 2][kq * 4];
            float4 A3 = *(const float4*)&As[ty * 4 + 3][kq * 4];
            float4 B0 = *(const float4*)&Bs[kq * 4 + 0][tx * 4];
            float4 B1 = *(const float4*)&Bs[kq * 4 + 1][tx * 4];
            float4 B2 = *(const float4*)&Bs[kq * 4 + 2][tx * 4];
            float4 B3 = *(const float4*)&Bs[kq * 4 + 3][tx * 4];
            QSTEP(x, B0); QSTEP(y, B1); QSTEP(z, B2); QSTEP(w, B3);
        }
        __syncthreads();
    }

    float* Ob = Dout + b * N * N;
#pragma unroll
    for (int r = 0; r < 4; ++r) {
        float4 v = make_float4(acc[r][0], acc[r][1], acc[r][2], acc[r][3]);
        *(float4*)&Ob[(bi * 64 + ty * 4 + r) * N + bj * 64 + tx * 4] = v;
    }
}

// ---------------------------------------------------------------------------
// per row (b,i): select 32 smallest (value,index) keys, emit indices in
// ascending index order == sort(stable_argsort(D_row)[:32]).
// ---------------------------------------------------------------------------
__global__ __launch_bounds__(256) void k_select(const float* __restrict__ D,
                                                int* __restrict__ nbr) {
    int row = blockIdx.x;           // b*N + i
    int j = threadIdx.x;

    __shared__ unsigned long long keys[256];
    __shared__ int wsum[4];

    float d = D[row * N + j];
    unsigned long long key =
        ((unsigned long long)__float_as_uint(d) << 32) | (unsigned int)j;
    keys[j] = key;
    __syncthreads();

    int cnt = 0;
#pragma unroll 16
    for (int t = 0; t < 256; ++t) cnt += (keys[t] < key) ? 1 : 0;

    bool flag = (cnt < NB);
    unsigned long long m = __ballot(flag);
    int lane = j & 63;
    int wid = j >> 6;
    if (lane == 0) wsum[wid] = __popcll(m);
    __syncthreads();
    int base = 0;
    for (int w = 0; w < wid; ++w) base += wsum[w];
    int pos = base + __popcll(m & ((1ull << lane) - 1ull));
    if (flag) nbr[row * NB + pos] = j;
}

// ---------------------------------------------------------------------------
// sub_f[b,i,r,:] = features[b, nbr[b,i,r], :]
// ---------------------------------------------------------------------------
__global__ __launch_bounds__(256) void k_gather_f(const float* __restrict__ feat,
                                                  const int* __restrict__ nbr,
                                                  float* __restrict__ outF) {
    int gid = blockIdx.x * blockDim.x + threadIdx.x;   // B*N*NB*(F/4)
    if (gid >= B * N * NB * (F / 4)) return;
    int c4  = gid & 31;
    int r   = (gid >> 5) & 31;
    int row = gid >> 10;
    int b   = row >> 8;
    int nj = nbr[row * NB + r];
    float4 v = *(const float4*)&feat[((b << 8) + nj) * F + (c4 << 2)];
    ((float4*)outF)[gid] = v;
}

// ---------------------------------------------------------------------------
// sub_a[b,i,r,c] = adj[b,nr,nc];  sub_e[b,i,r,c,:] = ef[b,nr,nc,:]
// ---------------------------------------------------------------------------
__global__ __launch_bounds__(256) void k_gather_ae(const float* __restrict__ adj,
                                                   const float* __restrict__ ef,
                                                   const int* __restrict__ nbr,
                                                   float* __restrict__ outA,
                                                   float* __restrict__ outE) {
    int gid = blockIdx.x * blockDim.x + threadIdx.x;   // B*N*NB*NB
    if (gid >= B * N * NB * NB) return;
    int c   = gid & 31;
    int r   = (gid >> 5) & 31;
    int row = gid >> 10;
    int b   = row >> 8;
    int nr = nbr[row * NB + r];
    int nc = nbr[row * NB + c];
    int base = (b << 16) + (nr << 8) + nc;
    outA[gid] = adj[base];
    const float* e = ef + (long)base * 3;
    float e0 = e[0], e1 = e[1], e2 = e[2];
    long og = (long)gid * 3;
    outE[og + 0] = e0;
    outE[og + 1] = e1;
    outE[og + 2] = e2;
}

// ---------------------------------------------------------------------------
extern "C" void kernel_launch(void* const* d_in, const int* in_sizes, int n_in,
                              void* d_out, int out_size, void* d_ws, size_t ws_size,
                              hipStream_t stream) {
    const float* feat = (const float*)d_in[0];   // (B,N,F)
    const float* adj  = (const float*)d_in[1];   // (B,N,N)
    const float* ef   = (const float*)d_in[2];   // (B,N,N,3)

    float* out  = (float*)d_out;
    float* outF = out;                                   // B*N*NB*F
    float* outA = out + (size_t)B * N * NB * F;          // B*N*NB*NB
    float* outE = outA + (size_t)B * N * NB * NB;        // B*N*NB*NB*3

    float* D0 = (float*)d_ws;
    float* D1 = D0 + (size_t)B * N * N;
    int*  nbr = (int*)(D1 + (size_t)B * N * N);

    // step 1 fuses the init transform; 8 squarings total like the reference
    k_minplus<true><<<B * 16, 256, 0, stream>>>(adj, D1);
    float* src = D1;
    float* dst = D0;
    for (int s = 1; s < 8; ++s) {
        k_minplus<false><<<B * 16, 256, 0, stream>>>(src, dst);
        float* t = src; src = dst; dst = t;
    }
    // s1:D1 s2:D0 s3:D1 s4:D0 s5:D1 s6:D0 s7:D1 s8:D0 -> final in src==D0

    k_select<<<B * N, 256, 0, stream>>>(src, nbr);

    k_gather_f<<<(B * N * NB * (F / 4)) / 256, 256, 0, stream>>>(feat, nbr, outF);
    k_gather_ae<<<(B * N * NB * NB) / 256, 256, 0, stream>>>(adj, ef, nbr, outA, outE);
}

// Round 3
// 183.520 us; speedup vs baseline: 1.3053x; 1.2604x over previous
//
#include <hip/hip_runtime.h>

#define B  16
#define N  256
#define F  128
#define NB 32
#define INF_F 1000000000.0f

// where(adj>0, adj, INF), then diag=0 (diag wins, like the reference)
#define XFORM(v, gi, gk) (((gi) == (gk)) ? 0.0f : (((v) > 0.0f) ? (v) : INF_F))

// ---------------------------------------------------------------------------
// min-plus squaring step, K-split x2: block (b,bi,bj,ks) computes
//   P_ks[i,j] = min_{k in [ks*128,(ks+1)*128)} S[i,k] + S[k,j]
// where S = XFORM(adj) on the first step, else fminf(S0,S1) (exact, since
// min-reduction reassociation is bitwise exact; the adds are never
// reassociated). 512 blocks -> 2 blocks/CU, 8 waves/CU.
// ---------------------------------------------------------------------------
template<bool FIRST>
__global__ __launch_bounds__(256) void k_minplus(const float* __restrict__ S0,
                                                 const float* __restrict__ S1,
                                                 float* __restrict__ O0,
                                                 float* __restrict__ O1) {
    int blk = blockIdx.x;           // B*4*4*2 = 512
    int ks = blk & 1;
    int bj = (blk >> 1) & 3;
    int bi = (blk >> 3) & 3;
    int b  = blk >> 5;
    int bofs = b * N * N;

    __shared__ float As[64][36];    // [i][k] padded: b128 reads 2-way (free)
    __shared__ float Bs[32][64];    // [k][j]

    int tid = threadIdx.x;
    int tx = tid & 15;
    int ty = tid >> 4;

    float acc[4][4];
#pragma unroll
    for (int r = 0; r < 4; ++r)
#pragma unroll
        for (int c = 0; c < 4; ++c) acc[r][c] = 3.0e38f;

    float ra[8], rb[8];

#define LOAD_A(kbase, u) {                                                     \
        int lin = (u) * 256 + tid;                                             \
        int gi = bi * 64 + (lin >> 5);                                         \
        int gk = (kbase) + (lin & 31);                                         \
        int idx = bofs + gi * N + gk;                                          \
        float v;                                                               \
        if (FIRST) { v = S0[idx]; v = XFORM(v, gi, gk); }                      \
        else       { v = fminf(S0[idx], S1[idx]); }                            \
        ra[u] = v; }
#define LOAD_B(kbase, u) {                                                     \
        int lin = (u) * 256 + tid;                                             \
        int gk = (kbase) + (lin >> 6);                                         \
        int gj = bj * 64 + (lin & 63);                                         \
        int idx = bofs + gk * N + gj;                                          \
        float v;                                                               \
        if (FIRST) { v = S0[idx]; v = XFORM(v, gk, gj); }                      \
        else       { v = fminf(S0[idx], S1[idx]); }                            \
        rb[u] = v; }

    int kb0 = ks * 128;
#pragma unroll
    for (int u = 0; u < 8; ++u) { LOAD_A(kb0, u) LOAD_B(kb0, u) }

    for (int kt = 0; kt < 4; ++kt) {
#pragma unroll
        for (int u = 0; u < 8; ++u) {
            int lin = u * 256 + tid;
            As[lin >> 5][lin & 31] = ra[u];
            Bs[lin >> 6][lin & 63] = rb[u];
        }
        __syncthreads();
        if (kt < 3) {
            int kb = kb0 + (kt + 1) * 32;
#pragma unroll
            for (int u = 0; u < 8; ++u) { LOAD_A(kb, u) LOAD_B(kb, u) }
        }

#define UPD(r, c, av, bv) acc[r][c] = fminf(acc[r][c], (av) + (bv))
#define QSTEP(comp, Bq)                                                        \
        UPD(0,0,A0.comp,Bq.x); UPD(0,1,A0.comp,Bq.y);                          \
        UPD(0,2,A0.comp,Bq.z); UPD(0,3,A0.comp,Bq.w);                          \
        UPD(1,0,A1.comp,Bq.x); UPD(1,1,A1.comp,Bq.y);                          \
        UPD(1,2,A1.comp,Bq.z); UPD(1,3,A1.comp,Bq.w);                          \
        UPD(2,0,A2.comp,Bq.x); UPD(2,1,A2.comp,Bq.y);                          \
        UPD(2,2,A2.comp,Bq.z); UPD(2,3,A2.comp,Bq.w);                          \
        UPD(3,0,A3.comp,Bq.x); UPD(3,1,A3.comp,Bq.y);                          \
        UPD(3,2,A3.comp,Bq.z); UPD(3,3,A3.comp,Bq.w)

#pragma unroll
        for (int kq = 0; kq < 8; ++kq) {
            float4 A0 = *(const float4*)&As[ty * 4 + 0][kq * 4];
            float4 A1 = *(const float4*)&As[ty * 4 + 1][kq * 4];
            float4 A2 = *(const float4*)&As[ty * 4 + 2][kq * 4];
            float4 A3 = *(const float4*)&As[ty * 4 + 3][kq * 4];
            float4 B0 = *(const float4*)&Bs[kq * 4 + 0][tx * 4];
            float4 B1 = *(const float4*)&Bs[kq * 4 + 1][tx * 4];
            float4 B2 = *(const float4*)&Bs[kq * 4 + 2][tx * 4];
            float4 B3 = *(const float4*)&Bs[kq * 4 + 3][tx * 4];
            QSTEP(x, B0); QSTEP(y, B1); QSTEP(z, B2); QSTEP(w, B3);
        }
        __syncthreads();
    }

    float* Ob = (ks ? O1 : O0) + bofs;
#pragma unroll
    for (int r = 0; r < 4; ++r) {
        float4 v = make_float4(acc[r][0], acc[r][1], acc[r][2], acc[r][3]);
        *(float4*)&Ob[(bi * 64 + ty * 4 + r) * N + bj * 64 + tx * 4] = v;
    }
}

// ---------------------------------------------------------------------------
// per row (b,i): radix-select the 32 smallest (value,index) keys, emit
// indices ascending. Greedy bit-search for v* = max T with count(u<T) <= 31
// (== bits of the 32nd-smallest value; uint order == float order for d>=0),
// then take {u < v*} plus the first (32 - count_less) ties in index order.
// Exactly reproduces sort(stable_argsort(D_row)[:32]).
// ---------------------------------------------------------------------------
__global__ __launch_bounds__(256) void k_select(const float* __restrict__ D0,
                                                const float* __restrict__ D1,
                                                int* __restrict__ nbr) {
    int row = blockIdx.x;           // b*N + i
    int j = threadIdx.x;
    int lane = j & 63;
    int wid = j >> 6;

    __shared__ int wcnt[4], weq[4], wsel[4];

    float d = fminf(D0[row * N + j], D1[row * N + j]);
    unsigned u = __float_as_uint(d);   // d >= 0 -> monotone bits

    unsigned prefix = 0;
    for (int b = 31; b >= 0; --b) {
        unsigned cand = prefix | (1u << b);
        unsigned long long m = __ballot(u < cand);
        if (lane == 0) wcnt[wid] = __popcll(m);
        __syncthreads();
        int c = wcnt[0] + wcnt[1] + wcnt[2] + wcnt[3];
        if (c <= 31) prefix = cand;
        __syncthreads();
    }

    unsigned long long mlt = __ballot(u < prefix);
    unsigned long long meq = __ballot(u == prefix);
    if (lane == 0) { wcnt[wid] = __popcll(mlt); weq[wid] = __popcll(meq); }
    __syncthreads();
    int cless = wcnt[0] + wcnt[1] + wcnt[2] + wcnt[3];
    int need = 32 - cless;          // >= 1 by construction
    int eqbefore = 0;
    for (int w = 0; w < wid; ++w) eqbefore += weq[w];
    unsigned long long lmask = (lane == 63) ? ~0ull >> 1 : ((1ull << lane) - 1ull);
    int tie_rank = eqbefore + __popcll(meq & ((1ull << lane) - 1ull));
    bool flag = (u < prefix) || (u == prefix && tie_rank < need);

    unsigned long long msel = __ballot(flag);
    if (lane == 0) wsel[wid] = __popcll(msel);
    __syncthreads();
    int base = 0;
    for (int w = 0; w < wid; ++w) base += wsel[w];
    int pos = base + __popcll(msel & ((1ull << lane) - 1ull));
    if (flag) nbr[row * NB + pos] = j;
    (void)lmask;
}

// ---------------------------------------------------------------------------
// sub_f[b,i,r,:] = features[b, nbr[b,i,r], :]
// ---------------------------------------------------------------------------
__global__ __launch_bounds__(256) void k_gather_f(const float* __restrict__ feat,
                                                  const int* __restrict__ nbr,
                                                  float* __restrict__ outF) {
    int gid = blockIdx.x * blockDim.x + threadIdx.x;   // B*N*NB*(F/4)
    if (gid >= B * N * NB * (F / 4)) return;
    int c4  = gid & 31;
    int r   = (gid >> 5) & 31;
    int row = gid >> 10;
    int b   = row >> 8;
    int nj = nbr[row * NB + r];
    float4 v = *(const float4*)&feat[((b << 8) + nj) * F + (c4 << 2)];
    ((float4*)outF)[gid] = v;
}

// ---------------------------------------------------------------------------
// sub_a[b,i,r,c] = adj[b,nr,nc];  sub_e[b,i,r,c,:] = ef[b,nr,nc,:]
// ---------------------------------------------------------------------------
__global__ __launch_bounds__(256) void k_gather_ae(const float* __restrict__ adj,
                                                   const float* __restrict__ ef,
                                                   const int* __restrict__ nbr,
                                                   float* __restrict__ outA,
                                                   float* __restrict__ outE) {
    int gid = blockIdx.x * blockDim.x + threadIdx.x;   // B*N*NB*NB
    if (gid >= B * N * NB * NB) return;
    int c   = gid & 31;
    int r   = (gid >> 5) & 31;
    int row = gid >> 10;
    int b   = row >> 8;
    int nr = nbr[row * NB + r];
    int nc = nbr[row * NB + c];
    int base = (b << 16) + (nr << 8) + nc;
    outA[gid] = adj[base];
    float3 e = *(const float3*)&ef[(long)base * 3];
    *(float3*)&outE[(long)gid * 3] = e;
}

// ---------------------------------------------------------------------------
extern "C" void kernel_launch(void* const* d_in, const int* in_sizes, int n_in,
                              void* d_out, int out_size, void* d_ws, size_t ws_size,
                              hipStream_t stream) {
    const float* feat = (const float*)d_in[0];   // (B,N,F)
    const float* adj  = (const float*)d_in[1];   // (B,N,N)
    const float* ef   = (const float*)d_in[2];   // (B,N,N,3)

    float* out  = (float*)d_out;
    float* outF = out;                                   // B*N*NB*F
    float* outA = out + (size_t)B * N * NB * F;          // B*N*NB*NB
    float* outE = outA + (size_t)B * N * NB * NB;        // B*N*NB*NB*3

    const size_t M = (size_t)B * N * N;
    float* pa0 = (float*)d_ws;
    float* pa1 = pa0 + M;
    float* pb0 = pa1 + M;
    float* pb1 = pb0 + M;
    int*  nbr = (int*)(pb1 + M);

    // 8 squarings like the reference; each step K-split into two partials,
    // combined (exact min) during the next step's staging loads.
    k_minplus<true><<<512, 256, 0, stream>>>(adj, adj, pa0, pa1);
    float *s0 = pa0, *s1 = pa1, *t0 = pb0, *t1 = pb1;
    for (int s = 1; s < 8; ++s) {
        k_minplus<false><<<512, 256, 0, stream>>>(s0, s1, t0, t1);
        float* x;
        x = s0; s0 = t0; t0 = x;
        x = s1; s1 = t1; t1 = x;
    }
    // final pair in (s0, s1)

    k_select<<<B * N, 256, 0, stream>>>(s0, s1, nbr);

    k_gather_f<<<(B * N * NB * (F / 4)) / 256, 256, 0, stream>>>(feat, nbr, outF);
    k_gather_ae<<<(B * N * NB * NB) / 256, 256, 0, stream>>>(adj, ef, nbr, outA, outE);
}